// Round 5
// baseline (385.154 us; speedup 1.0000x reference)
//
#include <hip/hip_runtime.h>
#include <hip/hip_bf16.h>

#define N_TOK 16384
#define D_IN 1024
#define D_HID 256
#define D_OUT 1024
#define N_EXP 8
#define CNT_STRIDE 16   // pad expert counters to separate 64B cache lines

typedef float f32x4 __attribute__((ext_vector_type(4)));
typedef short s16x8 __attribute__((ext_vector_type(8)));
typedef short s16x4 __attribute__((ext_vector_type(4)));

__device__ __forceinline__ short f2bf(float f) {
    unsigned u = __builtin_bit_cast(unsigned, f);
    u += 0x7FFF + ((u >> 16) & 1);   // round-to-nearest-even
    return (short)(u >> 16);
}

// ---------------- repack weights into MFMA-fragment-contiguous layout ----------------
// src W [E][K][N] (k-major). For n-tile nt, k-step kk (K=32 per step):
// WF[e][(nt*(K/32) + kk)*512 + lane*8 + j] = bf16(W[e][kk*32 + (lane>>4)*8 + j][nt*16 + (lane&15)])
// Also zeroes the expert counters (block 0) — stream-ordered before gate_kernel.
__global__ __launch_bounds__(256) void repack_kernel(
    const float* __restrict__ W, short* __restrict__ WF, int K, int N,
    int* __restrict__ cnt)
{
    if (blockIdx.x == 0 && blockIdx.y == 0 && threadIdx.x < N_EXP * CNT_STRIDE)
        cnt[threadIdx.x] = 0;
    int e = blockIdx.y;
    int nt = blockIdx.x;
    int nkk = K >> 5;
    const float* we = W + (size_t)e * K * N;
    short* wfe = WF + (size_t)e * (N >> 4) * nkk * 512;
    int kl = threadIdx.x >> 6;      // 0..3: kk within group of 4
    int lane = threadIdx.x & 63;
    int q = lane >> 4, m = lane & 15;
    for (int k0 = 0; k0 < nkk; k0 += 4) {
        int kk = k0 + kl;
        s16x8 pk;
        #pragma unroll
        for (int j = 0; j < 8; ++j)
            pk[j] = f2bf(we[(size_t)(kk * 32 + q * 8 + j) * N + nt * 16 + m]);
        *(s16x8*)&wfe[((size_t)nt * nkk + kk) * 512 + lane * 8] = pk;
    }
}

// ---------------- gating (fused with x -> bf16 conversion) ----------------
#define G_TOK 32                 // tokens per block (4 waves x 8 tokens)
__global__ __launch_bounds__(256) void gate_kernel(
    const float* __restrict__ x, const float* __restrict__ Wg,
    const float* __restrict__ bg, float* __restrict__ gate_out,
    int* __restrict__ cnt, int* __restrict__ lists,
    int* __restrict__ meta_e, float* __restrict__ meta_w,
    short* __restrict__ xb)
{
    __shared__ float wgs[D_IN * 12];
    __shared__ int lcnt[N_EXP];
    __shared__ int sbase[N_EXP];
    __shared__ int ent_e[2 * G_TOK];
    __shared__ int ent_r[2 * G_TOK];

    int tid = threadIdx.x;
    #pragma unroll
    for (int i = 0; i < 8; ++i) {
        int flat = i * 256 + tid;          // float4 index 0..2047
        int d = flat >> 1, j = (flat & 1) * 4;
        float4 v = *(const float4*)&Wg[d * 8 + j];
        *(float4*)&wgs[d * 12 + j] = v;
    }
    if (tid < N_EXP) lcnt[tid] = 0;
    __syncthreads();

    int lane = tid & 63, wv = tid >> 6;
    int tbase = blockIdx.x * G_TOK;

    for (int i = 0; i < G_TOK / 4; ++i) {
        int lt = wv * (G_TOK / 4) + i;
        int t = tbase + lt;
        const float* xr = x + (size_t)t * D_IN;
        float acc[8] = {0.f, 0.f, 0.f, 0.f, 0.f, 0.f, 0.f, 0.f};
        #pragma unroll
        for (int it = 0; it < 4; ++it) {
            int d0 = it * 256 + lane * 4;
            f32x4 v = __builtin_nontemporal_load((const f32x4*)&xr[d0]);
            s16x4 pk;
            pk[0] = f2bf(v[0]); pk[1] = f2bf(v[1]); pk[2] = f2bf(v[2]); pk[3] = f2bf(v[3]);
            *(s16x4*)&xb[(size_t)t * D_IN + d0] = pk;
            #pragma unroll
            for (int j = 0; j < 4; ++j) {
                int d = d0 + j;
                float4 wa = *(const float4*)&wgs[d * 12 + 0];
                float4 wb = *(const float4*)&wgs[d * 12 + 4];
                acc[0] += v[j] * wa.x; acc[1] += v[j] * wa.y;
                acc[2] += v[j] * wa.z; acc[3] += v[j] * wa.w;
                acc[4] += v[j] * wb.x; acc[5] += v[j] * wb.y;
                acc[6] += v[j] * wb.z; acc[7] += v[j] * wb.w;
            }
        }
        #pragma unroll
        for (int e = 0; e < 8; ++e) {
            #pragma unroll
            for (int off = 32; off >= 1; off >>= 1)
                acc[e] += __shfl_xor(acc[e], off);
        }
        if (lane == 0) {
            float lg[8];
            #pragma unroll
            for (int e = 0; e < 8; ++e) {
                lg[e] = acc[e] + bg[e];
                gate_out[(size_t)t * 8 + e] = lg[e];
            }
            int i0 = 0;
            #pragma unroll
            for (int e = 1; e < 8; ++e) if (lg[e] > lg[i0]) i0 = e;   // ties -> lowest idx
            int i1 = -1;
            #pragma unroll
            for (int e = 0; e < 8; ++e)
                if (e != i0 && (i1 < 0 || lg[e] > lg[i1])) i1 = e;
            float ex = expf(lg[i1] - lg[i0]);
            float inv = 1.f / (1.f + ex);
            meta_e[2 * t] = i0; meta_e[2 * t + 1] = i1;
            meta_w[2 * t] = inv; meta_w[2 * t + 1] = ex * inv;
            int r0 = atomicAdd(&lcnt[i0], 1);
            int r1 = atomicAdd(&lcnt[i1], 1);
            ent_e[2 * lt] = i0;     ent_r[2 * lt] = r0;
            ent_e[2 * lt + 1] = i1; ent_r[2 * lt + 1] = r1;
        }
    }
    __syncthreads();
    if (tid < N_EXP) sbase[tid] = atomicAdd(&cnt[tid * CNT_STRIDE], lcnt[tid]);
    __syncthreads();
    if (tid < 2 * G_TOK) {
        int e = ent_e[tid];
        lists[e * N_TOK + sbase[e] + ent_r[tid]] = tbase * 2 + tid;  // code = t*2 + slot
    }
}

// ---------------- expert MLP: 32-token tile, register-blocked bf16 MFMA ----------------
// BM=32: 1024 working blocks -> 4 blocks/CU (LDS ~34.5 KB, VGPR forced <=64 via
// __launch_bounds__(512,8)) = 32 waves/CU. TLP (not ILP) hides the L2 latency of
// the per-wave B-fragment streams. GEMM1: K=1024 in 4 dbuf chunks (T14 split:
// next-chunk loads issue before MFMAs, LDS-write after; 1 barrier/chunk).
// B-frags depth-2 prefetch, nontemporal x/out/ysc so weights stay L2-resident
// per XCD (e = blockIdx&7 == XCD id under round-robin dispatch).
// Epilogue: no atomics; slot-0 rows store into out, slot-1 rows into ysc.
#define BM 32
#define CLEN 256              // K-chunk (bf16 elements per row)
#define CLD 264               // 256+8: row stride 528 B -> conflict-free b128 reads
#define CHUNK_SH (BM * CLD)   // shorts per buffer (8448 -> 16896 B)
#define HLD 264

__global__ __launch_bounds__(512, 8) void expert_kernel(
    const short* __restrict__ xb,
    const short* __restrict__ W1F, const short* __restrict__ W2F,
    const float* __restrict__ b1,
    const int* __restrict__ cnt, const int* __restrict__ lists,
    const float* __restrict__ meta_w,
    float* __restrict__ ysc, float* __restrict__ out)
{
    int e = blockIdx.x & (N_EXP - 1);
    int me = cnt[e * CNT_STRIDE];
    int base = (blockIdx.x >> 3) * BM;
    if (base >= me) return;

    __shared__ short smem[2 * CHUNK_SH];   // xs double-buffer; buf0 aliased as hs
    short* hs = smem;
    __shared__ int toks[BM];
    __shared__ float wts[BM];
    __shared__ float* rowp[BM];        // per-row destination base (out or ysc)

    int tid = threadIdx.x;
    if (tid < BM) {
        int gi = base + tid;
        int enc = 0; float w = 0.f;
        if (gi < me) { enc = lists[e * N_TOK + gi]; w = meta_w[enc]; }
        toks[tid] = enc >> 1;
        wts[tid] = w;
        rowp[tid] = ((enc & 1) ? ysc : out) + (size_t)(enc >> 1) * D_OUT;
    }
    __syncthreads();

    int lane = tid & 63, wv = tid >> 6;
    int m = lane & 15, q = lane >> 4;

    const short* w1e = W1F + (size_t)e * (16 * 32 * 512);
    const short* w2e = W2F + (size_t)e * (64 * 8 * 512);

    // staging geometry: per chunk 32 rows x 32 segs(16B) = 1024 segs; 2/thread
    int c16 = tid & 31;
    const short* srcp[2];
    int rowoff[2];
    #pragma unroll
    for (int p = 0; p < 2; ++p) {
        int row = p * 16 + (tid >> 5);
        srcp[p] = xb + (size_t)toks[row] * D_IN + c16 * 8;
        rowoff[p] = row * CLD + c16 * 8;
    }

    // ---- GEMM1: H[32x256] = relu(X @ W1 + b1), K=1024 in 4 dbuf chunks ----
    f32x4 acc1[2][2];
    #pragma unroll
    for (int mt = 0; mt < 2; ++mt)
        #pragma unroll
        for (int ntl = 0; ntl < 2; ++ntl)
            acc1[mt][ntl] = (f32x4){0.f, 0.f, 0.f, 0.f};

    const short* wp0 = w1e + ((size_t)(wv * 2 + 0) * 32) * 512 + lane * 8;
    const short* wp1 = w1e + ((size_t)(wv * 2 + 1) * 32) * 512 + lane * 8;

    // prologue: stage chunk 0, preload b-frags kg=0,1
    #pragma unroll
    for (int p = 0; p < 2; ++p) {
        s16x8 v = __builtin_nontemporal_load((const s16x8*)srcp[p]);
        *(s16x8*)&smem[rowoff[p]] = v;
    }
    s16x8 bq0[2], bq1[2];
    bq0[0] = *(const s16x8*)(wp0);
    bq1[0] = *(const s16x8*)(wp1);
    bq0[1] = *(const s16x8*)(wp0 + 512);
    bq1[1] = *(const s16x8*)(wp1 + 512);
    __syncthreads();

    #pragma unroll
    for (int c = 0; c < 4; ++c) {
        const short* cs = &smem[(c & 1) * CHUNK_SH];
        // T14: issue next-chunk global loads before compute
        s16x8 st[2];
        if (c < 3) {
            #pragma unroll
            for (int p = 0; p < 2; ++p)
                st[p] = __builtin_nontemporal_load((const s16x8*)(srcp[p] + (c + 1) * CLEN));
        }
        #pragma unroll
        for (int kk = 0; kk < 8; ++kk) {
            int kg = c * 8 + kk;
            s16x8 bc0 = bq0[kg & 1], bc1 = bq1[kg & 1];
            if (kg < 30) {
                bq0[kg & 1] = *(const s16x8*)(wp0 + (size_t)(kg + 2) * 512);
                bq1[kg & 1] = *(const s16x8*)(wp1 + (size_t)(kg + 2) * 512);
            }
            s16x8 a[2];
            #pragma unroll
            for (int mt = 0; mt < 2; ++mt)
                a[mt] = *(const s16x8*)&cs[(mt * 16 + m) * CLD + kk * 32 + q * 8];
            #pragma unroll
            for (int mt = 0; mt < 2; ++mt)
                acc1[mt][0] = __builtin_amdgcn_mfma_f32_16x16x32_bf16(a[mt], bc0, acc1[mt][0], 0, 0, 0);
            #pragma unroll
            for (int mt = 0; mt < 2; ++mt)
                acc1[mt][1] = __builtin_amdgcn_mfma_f32_16x16x32_bf16(a[mt], bc1, acc1[mt][1], 0, 0, 0);
        }
        if (c < 3) {
            // write staged data into the other buffer (its readers finished
            // before the previous barrier), then sync
            short* nxt = &smem[((c + 1) & 1) * CHUNK_SH];
            #pragma unroll
            for (int p = 0; p < 2; ++p)
                *(s16x8*)&nxt[rowoff[p]] = st[p];
            __syncthreads();
        }
    }

    // ---- epilogue 1: bias + relu -> hs (aliases buf0; safe: last chunk read buf1) ----
    const float* b1e = b1 + (size_t)e * D_HID;
    #pragma unroll
    for (int ntl = 0; ntl < 2; ++ntl) {
        int j = wv * 32 + ntl * 16 + m;       // C/D: col = lane&15
        float bias = b1e[j];
        #pragma unroll
        for (int mt = 0; mt < 2; ++mt) {
            #pragma unroll
            for (int r = 0; r < 4; ++r) {
                int row = mt * 16 + q * 4 + r;  // C/D: row = (lane>>4)*4 + reg
                float h = acc1[mt][ntl][r] + bias;
                h = h > 0.f ? h : 0.f;
                hs[row * HLD + j] = f2bf(h);
            }
        }
    }
    __syncthreads();

    // ---- GEMM2: Y[32x1024] = H @ W2, K=256; 4 passes of 32 cols per wave ----
    const short* w2base = w2e + ((size_t)(wv * 8) * 8) * 512 + lane * 8;
    for (int pass = 0; pass < 4; ++pass) {
        f32x4 acc2[2][2];
        #pragma unroll
        for (int mt = 0; mt < 2; ++mt)
            #pragma unroll
            for (int ntl = 0; ntl < 2; ++ntl)
                acc2[mt][ntl] = (f32x4){0.f, 0.f, 0.f, 0.f};
        const short* p0 = w2base + (size_t)(pass * 2 + 0) * 8 * 512;
        const short* p1 = w2base + (size_t)(pass * 2 + 1) * 8 * 512;
        s16x8 cq0[2], cq1[2];
        cq0[0] = *(const s16x8*)(p0);
        cq1[0] = *(const s16x8*)(p1);
        cq0[1] = *(const s16x8*)(p0 + 512);
        cq1[1] = *(const s16x8*)(p1 + 512);
        #pragma unroll
        for (int kk = 0; kk < 8; ++kk) {
            s16x8 bc0 = cq0[kk & 1], bc1 = cq1[kk & 1];
            if (kk < 6) {
                cq0[kk & 1] = *(const s16x8*)(p0 + (size_t)(kk + 2) * 512);
                cq1[kk & 1] = *(const s16x8*)(p1 + (size_t)(kk + 2) * 512);
            }
            s16x8 a[2];
            #pragma unroll
            for (int mt = 0; mt < 2; ++mt)
                a[mt] = *(const s16x8*)&hs[(mt * 16 + m) * HLD + kk * 32 + q * 8];
            #pragma unroll
            for (int mt = 0; mt < 2; ++mt)
                acc2[mt][0] = __builtin_amdgcn_mfma_f32_16x16x32_bf16(a[mt], bc0, acc2[mt][0], 0, 0, 0);
            #pragma unroll
            for (int mt = 0; mt < 2; ++mt)
                acc2[mt][1] = __builtin_amdgcn_mfma_f32_16x16x32_bf16(a[mt], bc1, acc2[mt][1], 0, 0, 0);
        }
        // ---- epilogue 2: weighted nontemporal streaming stores (no atomics) ----
        #pragma unroll
        for (int ntl = 0; ntl < 2; ++ntl) {
            int col = (wv * 8 + pass * 2 + ntl) * 16 + m;
            #pragma unroll
            for (int mt = 0; mt < 2; ++mt) {
                #pragma unroll
                for (int r = 0; r < 4; ++r) {
                    int row = mt * 16 + q * 4 + r;
                    if (base + row < me)
                        __builtin_nontemporal_store(wts[row] * acc2[mt][ntl][r],
                                                    &rowp[row][col]);
                }
            }
        }
    }
}

// ---------------- combine: out[t] = slot0(out) + slot1(ysc) + w0*b2[e0] + w1*b2[e1] ----------------
#define C_TOK 8
__global__ __launch_bounds__(256) void combine_kernel(
    const int* __restrict__ meta_e, const float* __restrict__ meta_w,
    const float* __restrict__ b2, const float* __restrict__ ysc,
    float* __restrict__ out)
{
    int c = threadIdx.x * 4;
    int t0 = blockIdx.x * C_TOK;
    #pragma unroll
    for (int i = 0; i < C_TOK; ++i) {
        int t = t0 + i;
        int e0 = meta_e[2 * t], e1 = meta_e[2 * t + 1];
        float w0 = meta_w[2 * t], w1 = meta_w[2 * t + 1];
        f32x4 o  = __builtin_nontemporal_load((const f32x4*)&out[(size_t)t * D_OUT + c]);
        f32x4 y1 = __builtin_nontemporal_load((const f32x4*)&ysc[(size_t)t * D_OUT + c]);
        f32x4 a  = *(const f32x4*)&b2[(size_t)e0 * D_OUT + c];
        f32x4 b  = *(const f32x4*)&b2[(size_t)e1 * D_OUT + c];
        f32x4 r;
        r[0] = o[0] + y1[0] + w0 * a[0] + w1 * b[0];
        r[1] = o[1] + y1[1] + w0 * a[1] + w1 * b[1];
        r[2] = o[2] + y1[2] + w0 * a[2] + w1 * b[2];
        r[3] = o[3] + y1[3] + w0 * a[3] + w1 * b[3];
        __builtin_nontemporal_store(r, (f32x4*)&out[(size_t)t * D_OUT + c]);
    }
}

extern "C" void kernel_launch(void* const* d_in, const int* in_sizes, int n_in,
                              void* d_out, int out_size, void* d_ws, size_t ws_size,
                              hipStream_t stream) {
    const float* x  = (const float*)d_in[0];
    const float* Wg = (const float*)d_in[1];
    const float* bg = (const float*)d_in[2];
    const float* W1 = (const float*)d_in[3];
    const float* b1 = (const float*)d_in[4];
    const float* W2 = (const float*)d_in[5];
    const float* b2 = (const float*)d_in[6];

    float* out = (float*)d_out;                         // [16384,1024]
    float* gate_out = out + (size_t)N_TOK * D_OUT;      // [16384,8]

    // workspace layout (~105 MB)
    short* W1F   = (short*)d_ws;                        // [8][16*32*512] bf16 frag-major
    short* W2F   = W1F + (size_t)N_EXP * 16 * 32 * 512; // [8][64*8*512]
    int*   cnt   = (int*)(W2F + (size_t)N_EXP * 64 * 8 * 512);  // [8*16] padded
    int*   lists = cnt + N_EXP * CNT_STRIDE;            // [8][16384]
    int*   meta_e = lists + N_EXP * N_TOK;              // [16384][2]
    float* meta_w = (float*)(meta_e + 2 * N_TOK);       // [16384][2]
    float* ysc   = meta_w + 2 * N_TOK;                  // [16384][1024] slot-1 partials
    short* xb    = (short*)(ysc + (size_t)N_TOK * D_OUT); // [16384][1024] bf16 x

    repack_kernel<<<dim3(D_HID / 16, N_EXP), 256, 0, stream>>>(W1, W1F, D_IN, D_HID, cnt);
    repack_kernel<<<dim3(D_OUT / 16, N_EXP), 256, 0, stream>>>(W2, W2F, D_HID, D_OUT, cnt);
    gate_kernel<<<N_TOK / G_TOK, 256, 0, stream>>>(x, Wg, bg, gate_out, cnt, lists, meta_e, meta_w, xb);
    expert_kernel<<<(N_TOK / BM) * N_EXP, 512, 0, stream>>>(xb, W1F, W2F, b1, cnt, lists, meta_w, ysc, out);
    combine_kernel<<<N_TOK / C_TOK, 256, 0, stream>>>(meta_e, meta_w, b2, ysc, out);
}

// Round 6
// 259.134 us; speedup vs baseline: 1.4863x; 1.4863x over previous
//
#include <hip/hip_runtime.h>
#include <hip/hip_bf16.h>

#define N_TOK 16384
#define D_IN 1024
#define D_HID 256
#define D_OUT 1024
#define N_EXP 8
#define CNT_STRIDE 16   // pad expert counters to separate 64B cache lines

typedef float f32x4 __attribute__((ext_vector_type(4)));
typedef short s16x8 __attribute__((ext_vector_type(8)));
typedef short s16x4 __attribute__((ext_vector_type(4)));

__device__ __forceinline__ short f2bf(float f) {
    unsigned u = __builtin_bit_cast(unsigned, f);
    u += 0x7FFF + ((u >> 16) & 1);   // round-to-nearest-even
    return (short)(u >> 16);
}

// ---------------- repack weights into MFMA-fragment-contiguous layout ----------------
// src W [E][K][N] (k-major). For n-tile nt, k-step kk (K=32 per step):
// WF[e][(nt*(K/32) + kk)*512 + lane*8 + j] = bf16(W[e][kk*32 + (lane>>4)*8 + j][nt*16 + (lane&15)])
// Also zeroes the expert counters (block 0) — stream-ordered before gate_kernel.
__global__ __launch_bounds__(256) void repack_kernel(
    const float* __restrict__ W, short* __restrict__ WF, int K, int N,
    int* __restrict__ cnt)
{
    if (blockIdx.x == 0 && blockIdx.y == 0 && threadIdx.x < N_EXP * CNT_STRIDE)
        cnt[threadIdx.x] = 0;
    int e = blockIdx.y;
    int nt = blockIdx.x;
    int nkk = K >> 5;
    const float* we = W + (size_t)e * K * N;
    short* wfe = WF + (size_t)e * (N >> 4) * nkk * 512;
    int kl = threadIdx.x >> 6;      // 0..3: kk within group of 4
    int lane = threadIdx.x & 63;
    int q = lane >> 4, m = lane & 15;
    for (int k0 = 0; k0 < nkk; k0 += 4) {
        int kk = k0 + kl;
        s16x8 pk;
        #pragma unroll
        for (int j = 0; j < 8; ++j)
            pk[j] = f2bf(we[(size_t)(kk * 32 + q * 8 + j) * N + nt * 16 + m]);
        *(s16x8*)&wfe[((size_t)nt * nkk + kk) * 512 + lane * 8] = pk;
    }
}

// ---------------- gating (fused with x -> bf16 conversion) ----------------
#define G_TOK 32                 // tokens per block (4 waves x 8 tokens)
__global__ __launch_bounds__(256) void gate_kernel(
    const float* __restrict__ x, const float* __restrict__ Wg,
    const float* __restrict__ bg, float* __restrict__ gate_out,
    int* __restrict__ cnt, int* __restrict__ lists,
    int* __restrict__ meta_e, float* __restrict__ meta_w,
    short* __restrict__ xb)
{
    __shared__ float wgs[D_IN * 12];
    __shared__ int lcnt[N_EXP];
    __shared__ int sbase[N_EXP];
    __shared__ int ent_e[2 * G_TOK];
    __shared__ int ent_r[2 * G_TOK];

    int tid = threadIdx.x;
    #pragma unroll
    for (int i = 0; i < 8; ++i) {
        int flat = i * 256 + tid;          // float4 index 0..2047
        int d = flat >> 1, j = (flat & 1) * 4;
        float4 v = *(const float4*)&Wg[d * 8 + j];
        *(float4*)&wgs[d * 12 + j] = v;
    }
    if (tid < N_EXP) lcnt[tid] = 0;
    __syncthreads();

    int lane = tid & 63, wv = tid >> 6;
    int tbase = blockIdx.x * G_TOK;

    for (int i = 0; i < G_TOK / 4; ++i) {
        int lt = wv * (G_TOK / 4) + i;
        int t = tbase + lt;
        const float* xr = x + (size_t)t * D_IN;
        float acc[8] = {0.f, 0.f, 0.f, 0.f, 0.f, 0.f, 0.f, 0.f};
        #pragma unroll
        for (int it = 0; it < 4; ++it) {
            int d0 = it * 256 + lane * 4;
            f32x4 v = __builtin_nontemporal_load((const f32x4*)&xr[d0]);
            s16x4 pk;
            pk[0] = f2bf(v[0]); pk[1] = f2bf(v[1]); pk[2] = f2bf(v[2]); pk[3] = f2bf(v[3]);
            *(s16x4*)&xb[(size_t)t * D_IN + d0] = pk;
            #pragma unroll
            for (int j = 0; j < 4; ++j) {
                int d = d0 + j;
                float4 wa = *(const float4*)&wgs[d * 12 + 0];
                float4 wb = *(const float4*)&wgs[d * 12 + 4];
                acc[0] += v[j] * wa.x; acc[1] += v[j] * wa.y;
                acc[2] += v[j] * wa.z; acc[3] += v[j] * wa.w;
                acc[4] += v[j] * wb.x; acc[5] += v[j] * wb.y;
                acc[6] += v[j] * wb.z; acc[7] += v[j] * wb.w;
            }
        }
        #pragma unroll
        for (int e = 0; e < 8; ++e) {
            #pragma unroll
            for (int off = 32; off >= 1; off >>= 1)
                acc[e] += __shfl_xor(acc[e], off);
        }
        if (lane == 0) {
            float lg[8];
            #pragma unroll
            for (int e = 0; e < 8; ++e) {
                lg[e] = acc[e] + bg[e];
                gate_out[(size_t)t * 8 + e] = lg[e];
            }
            int i0 = 0;
            #pragma unroll
            for (int e = 1; e < 8; ++e) if (lg[e] > lg[i0]) i0 = e;   // ties -> lowest idx
            int i1 = -1;
            #pragma unroll
            for (int e = 0; e < 8; ++e)
                if (e != i0 && (i1 < 0 || lg[e] > lg[i1])) i1 = e;
            float ex = expf(lg[i1] - lg[i0]);
            float inv = 1.f / (1.f + ex);
            meta_e[2 * t] = i0; meta_e[2 * t + 1] = i1;
            meta_w[2 * t] = inv; meta_w[2 * t + 1] = ex * inv;
            int r0 = atomicAdd(&lcnt[i0], 1);
            int r1 = atomicAdd(&lcnt[i1], 1);
            ent_e[2 * lt] = i0;     ent_r[2 * lt] = r0;
            ent_e[2 * lt + 1] = i1; ent_r[2 * lt + 1] = r1;
        }
    }
    __syncthreads();
    if (tid < N_EXP) sbase[tid] = atomicAdd(&cnt[tid * CNT_STRIDE], lcnt[tid]);
    __syncthreads();
    if (tid < 2 * G_TOK) {
        int e = ent_e[tid];
        lists[e * N_TOK + sbase[e] + ent_r[tid]] = tbase * 2 + tid;  // code = t*2 + slot
    }
}

// ---------------- expert MLP: 64-token tile, register-blocked bf16 MFMA ----------------
// R4 structure (153us) + full-line epilogue: GEMM2 output staged through LDS
// (reusing staging buf1) so global stores are wave-contiguous 1KB bursts of
// full 128B lines. R4's scattered 64B partial-line stores caused ~1.65x write
// amplification AND ~130MB of L2 write-allocate line-fill reads (FETCH 178 vs
// ~48 ideal) — the shared saturated resource that made extra occupancy (R5)
// useless. nontemporal dropped on out/ysc (combine re-reads them; L3-friendly).
#define BM 64
#define CLEN 256              // K-chunk (bf16 elements per row)
#define CLD 264               // 256+8: row stride 528 B -> conflict-free b128 reads
#define CHUNK_SH (BM * CLD)   // shorts per buffer (16896 -> 33792 B)
#define HLD 264
#define YLD 260               // f32 row stride for Y staging (16B-aligned rows)

__global__ __launch_bounds__(512, 4) void expert_kernel(
    const short* __restrict__ xb,
    const short* __restrict__ W1F, const short* __restrict__ W2F,
    const float* __restrict__ b1,
    const int* __restrict__ cnt, const int* __restrict__ lists,
    const float* __restrict__ meta_w,
    float* __restrict__ ysc, float* __restrict__ out)
{
    int e = blockIdx.x & (N_EXP - 1);
    int me = cnt[e * CNT_STRIDE];
    int base = (blockIdx.x >> 3) * BM;
    if (base >= me) return;

    __shared__ short smem[2 * CHUNK_SH];   // xs double-buffer; buf0 aliased as hs
    short* hs = smem;
    float* yst = (float*)(smem + CHUNK_SH);   // 32 x YLD f32 Y-staging (in buf1)
    __shared__ int toks[BM];
    __shared__ float wts[BM];
    __shared__ float* rowp[BM];        // per-row destination base (out or ysc)

    int tid = threadIdx.x;
    if (tid < BM) {
        int gi = base + tid;
        int enc = 0; float w = 0.f;
        if (gi < me) { enc = lists[e * N_TOK + gi]; w = meta_w[enc]; }
        toks[tid] = enc >> 1;
        wts[tid] = w;
        rowp[tid] = ((enc & 1) ? ysc : out) + (size_t)(enc >> 1) * D_OUT;
    }
    __syncthreads();

    int lane = tid & 63, wv = tid >> 6;
    int m = lane & 15, q = lane >> 4;

    const short* w1e = W1F + (size_t)e * (16 * 32 * 512);
    const short* w2e = W2F + (size_t)e * (64 * 8 * 512);

    // staging geometry: per chunk 64 rows x 32 segs(16B); 4 segs/thread
    int c16 = tid & 31;
    const short* srcp[4];
    int rowoff[4];
    #pragma unroll
    for (int p = 0; p < 4; ++p) {
        int row = p * 16 + (tid >> 5);
        srcp[p] = xb + (size_t)toks[row] * D_IN + c16 * 8;
        rowoff[p] = row * CLD + c16 * 8;
    }

    // ---- GEMM1: H[64x256] = relu(X @ W1 + b1), K=1024 in 4 dbuf chunks ----
    f32x4 acc1[4][2];
    #pragma unroll
    for (int mt = 0; mt < 4; ++mt)
        #pragma unroll
        for (int ntl = 0; ntl < 2; ++ntl)
            acc1[mt][ntl] = (f32x4){0.f, 0.f, 0.f, 0.f};

    const short* wp0 = w1e + ((size_t)(wv * 2 + 0) * 32) * 512 + lane * 8;
    const short* wp1 = w1e + ((size_t)(wv * 2 + 1) * 32) * 512 + lane * 8;

    // prologue: stage chunk 0, preload b-frags kg=0,1
    #pragma unroll
    for (int p = 0; p < 4; ++p) {
        s16x8 v = __builtin_nontemporal_load((const s16x8*)srcp[p]);
        *(s16x8*)&smem[rowoff[p]] = v;
    }
    s16x8 bq0[2], bq1[2];
    bq0[0] = *(const s16x8*)(wp0);
    bq1[0] = *(const s16x8*)(wp1);
    bq0[1] = *(const s16x8*)(wp0 + 512);
    bq1[1] = *(const s16x8*)(wp1 + 512);
    __syncthreads();

    #pragma unroll
    for (int c = 0; c < 4; ++c) {
        const short* cs = &smem[(c & 1) * CHUNK_SH];
        // T14: issue next-chunk global loads before compute
        s16x8 st[4];
        if (c < 3) {
            #pragma unroll
            for (int p = 0; p < 4; ++p)
                st[p] = __builtin_nontemporal_load((const s16x8*)(srcp[p] + (c + 1) * CLEN));
        }
        #pragma unroll
        for (int kk = 0; kk < 8; ++kk) {
            int kg = c * 8 + kk;
            s16x8 bc0 = bq0[kg & 1], bc1 = bq1[kg & 1];
            if (kg < 30) {
                bq0[kg & 1] = *(const s16x8*)(wp0 + (size_t)(kg + 2) * 512);
                bq1[kg & 1] = *(const s16x8*)(wp1 + (size_t)(kg + 2) * 512);
            }
            s16x8 a[4];
            #pragma unroll
            for (int mt = 0; mt < 4; ++mt)
                a[mt] = *(const s16x8*)&cs[(mt * 16 + m) * CLD + kk * 32 + q * 8];
            #pragma unroll
            for (int mt = 0; mt < 4; ++mt)
                acc1[mt][0] = __builtin_amdgcn_mfma_f32_16x16x32_bf16(a[mt], bc0, acc1[mt][0], 0, 0, 0);
            #pragma unroll
            for (int mt = 0; mt < 4; ++mt)
                acc1[mt][1] = __builtin_amdgcn_mfma_f32_16x16x32_bf16(a[mt], bc1, acc1[mt][1], 0, 0, 0);
        }
        if (c < 3) {
            // write staged data into the other buffer (its readers finished
            // before the previous barrier), then sync
            short* nxt = &smem[((c + 1) & 1) * CHUNK_SH];
            #pragma unroll
            for (int p = 0; p < 4; ++p)
                *(s16x8*)&nxt[rowoff[p]] = st[p];
            __syncthreads();
        }
    }

    // ---- epilogue 1: bias + relu -> hs (aliases buf0; safe: last chunk read buf1) ----
    const float* b1e = b1 + (size_t)e * D_HID;
    #pragma unroll
    for (int ntl = 0; ntl < 2; ++ntl) {
        int j = wv * 32 + ntl * 16 + m;       // C/D: col = lane&15
        float bias = b1e[j];
        #pragma unroll
        for (int mt = 0; mt < 4; ++mt) {
            #pragma unroll
            for (int r = 0; r < 4; ++r) {
                int row = mt * 16 + q * 4 + r;  // C/D: row = (lane>>4)*4 + reg
                float h = acc1[mt][ntl][r] + bias;
                h = h > 0.f ? h : 0.f;
                hs[row * HLD + j] = f2bf(h);
            }
        }
    }
    __syncthreads();

    // ---- GEMM2: Y[64x1024] = H @ W2, K=256; 4 passes of 32 cols per wave ----
    const short* w2base = w2e + ((size_t)(wv * 8) * 8) * 512 + lane * 8;
    for (int pass = 0; pass < 4; ++pass) {
        f32x4 acc2[4][2];
        #pragma unroll
        for (int mt = 0; mt < 4; ++mt)
            #pragma unroll
            for (int ntl = 0; ntl < 2; ++ntl)
                acc2[mt][ntl] = (f32x4){0.f, 0.f, 0.f, 0.f};
        const short* p0 = w2base + (size_t)(pass * 2 + 0) * 8 * 512;
        const short* p1 = w2base + (size_t)(pass * 2 + 1) * 8 * 512;
        s16x8 cq0[2], cq1[2];
        cq0[0] = *(const s16x8*)(p0);
        cq1[0] = *(const s16x8*)(p1);
        cq0[1] = *(const s16x8*)(p0 + 512);
        cq1[1] = *(const s16x8*)(p1 + 512);
        #pragma unroll
        for (int kk = 0; kk < 8; ++kk) {
            s16x8 bc0 = cq0[kk & 1], bc1 = cq1[kk & 1];
            if (kk < 6) {
                cq0[kk & 1] = *(const s16x8*)(p0 + (size_t)(kk + 2) * 512);
                cq1[kk & 1] = *(const s16x8*)(p1 + (size_t)(kk + 2) * 512);
            }
            s16x8 a[4];
            #pragma unroll
            for (int mt = 0; mt < 4; ++mt)
                a[mt] = *(const s16x8*)&hs[(mt * 16 + m) * HLD + kk * 32 + q * 8];
            #pragma unroll
            for (int mt = 0; mt < 4; ++mt)
                acc2[mt][0] = __builtin_amdgcn_mfma_f32_16x16x32_bf16(a[mt], bc0, acc2[mt][0], 0, 0, 0);
            #pragma unroll
            for (int mt = 0; mt < 4; ++mt)
                acc2[mt][1] = __builtin_amdgcn_mfma_f32_16x16x32_bf16(a[mt], bc1, acc2[mt][1], 0, 0, 0);
        }
        // ---- epilogue 2: stage Y through LDS, write full 128B lines ----
        // pass covers global cols band(b)*128 + pass*32 .. +32 for b=0..7
        // (band b == wave wv that produced it). Two halves of 32 rows each.
        #pragma unroll
        for (int half = 0; half < 2; ++half) {
            // write my fragment rows [half*32, half*32+32) into yst (weighted)
            #pragma unroll
            for (int ntl = 0; ntl < 2; ++ntl) {
                int cc = wv * 32 + ntl * 16 + m;       // compact col
                #pragma unroll
                for (int mtl = 0; mtl < 2; ++mtl) {
                    int mt = half * 2 + mtl;
                    #pragma unroll
                    for (int r = 0; r < 4; ++r) {
                        int lr = mtl * 16 + q * 4 + r;          // local row 0..31
                        int grow = mt * 16 + q * 4 + r;         // tile row
                        yst[lr * YLD + cc] = wts[grow] * acc2[mt][ntl][r];
                    }
                }
            }
            __syncthreads();
            // readback: wave-contiguous 1KB bursts -> full 128B lines
            #pragma unroll
            for (int i = 0; i < 4; ++i) {
                int lr = i * 8 + wv;                    // local row 0..31
                int gr = half * 32 + lr;                // tile row
                int cc = lane * 4;                      // compact col, step 4
                int gc = (cc >> 5) * 128 + pass * 32 + (cc & 31);
                if (base + gr < me) {
                    f32x4 v = *(const f32x4*)&yst[lr * YLD + cc];
                    *(f32x4*)&rowp[gr][gc] = v;
                }
            }
            __syncthreads();   // protect yst before next half/pass overwrites
        }
    }
}

// ---------------- combine: out[t] = slot0(out) + slot1(ysc) + w0*b2[e0] + w1*b2[e1] ----------------
#define C_TOK 8
__global__ __launch_bounds__(256) void combine_kernel(
    const int* __restrict__ meta_e, const float* __restrict__ meta_w,
    const float* __restrict__ b2, const float* __restrict__ ysc,
    float* __restrict__ out)
{
    int c = threadIdx.x * 4;
    int t0 = blockIdx.x * C_TOK;
    #pragma unroll
    for (int i = 0; i < C_TOK; ++i) {
        int t = t0 + i;
        int e0 = meta_e[2 * t], e1 = meta_e[2 * t + 1];
        float w0 = meta_w[2 * t], w1 = meta_w[2 * t + 1];
        f32x4 o  = *(const f32x4*)&out[(size_t)t * D_OUT + c];
        f32x4 y1 = *(const f32x4*)&ysc[(size_t)t * D_OUT + c];
        f32x4 a  = *(const f32x4*)&b2[(size_t)e0 * D_OUT + c];
        f32x4 b  = *(const f32x4*)&b2[(size_t)e1 * D_OUT + c];
        f32x4 r;
        r[0] = o[0] + y1[0] + w0 * a[0] + w1 * b[0];
        r[1] = o[1] + y1[1] + w0 * a[1] + w1 * b[1];
        r[2] = o[2] + y1[2] + w0 * a[2] + w1 * b[2];
        r[3] = o[3] + y1[3] + w0 * a[3] + w1 * b[3];
        *(f32x4*)&out[(size_t)t * D_OUT + c] = r;
    }
}

extern "C" void kernel_launch(void* const* d_in, const int* in_sizes, int n_in,
                              void* d_out, int out_size, void* d_ws, size_t ws_size,
                              hipStream_t stream) {
    const float* x  = (const float*)d_in[0];
    const float* Wg = (const float*)d_in[1];
    const float* bg = (const float*)d_in[2];
    const float* W1 = (const float*)d_in[3];
    const float* b1 = (const float*)d_in[4];
    const float* W2 = (const float*)d_in[5];
    const float* b2 = (const float*)d_in[6];

    float* out = (float*)d_out;                         // [16384,1024]
    float* gate_out = out + (size_t)N_TOK * D_OUT;      // [16384,8]

    // workspace layout (~105 MB)
    short* W1F   = (short*)d_ws;                        // [8][16*32*512] bf16 frag-major
    short* W2F   = W1F + (size_t)N_EXP * 16 * 32 * 512; // [8][64*8*512]
    int*   cnt   = (int*)(W2F + (size_t)N_EXP * 64 * 8 * 512);  // [8*16] padded
    int*   lists = cnt + N_EXP * CNT_STRIDE;            // [8][16384]
    int*   meta_e = lists + N_EXP * N_TOK;              // [16384][2]
    float* meta_w = (float*)(meta_e + 2 * N_TOK);       // [16384][2]
    float* ysc   = meta_w + 2 * N_TOK;                  // [16384][1024] slot-1 partials
    short* xb    = (short*)(ysc + (size_t)N_TOK * D_OUT); // [16384][1024] bf16 x

    repack_kernel<<<dim3(D_HID / 16, N_EXP), 256, 0, stream>>>(W1, W1F, D_IN, D_HID, cnt);
    repack_kernel<<<dim3(D_OUT / 16, N_EXP), 256, 0, stream>>>(W2, W2F, D_HID, D_OUT, cnt);
    gate_kernel<<<N_TOK / G_TOK, 256, 0, stream>>>(x, Wg, bg, gate_out, cnt, lists, meta_e, meta_w, xb);
    expert_kernel<<<(N_TOK / BM) * N_EXP, 512, 0, stream>>>(xb, W1F, W2F, b1, cnt, lists, meta_w, ysc, out);
    combine_kernel<<<N_TOK / C_TOK, 256, 0, stream>>>(meta_e, meta_w, b2, ysc, out);
}